// Round 2
// baseline (579.950 us; speedup 1.0000x reference)
//
#include <hip/hip_runtime.h>

#define T_LEN 100
#define H 32
#define L 6
#define NT 6          // 96 gate rows / 16
#define TPB 512       // 8 waves: SIMD s hosts waves {s, s+4}
#define BT 32         // two independent 16-batch groups per block
#define S1 1.44269504088896f   // log2(e)

typedef float f32x4  __attribute__((ext_vector_type(4)));
typedef short bf16x8 __attribute__((ext_vector_type(8)));

union FragU { bf16x8 s; f32x4 f; unsigned int u[4]; };

__device__ inline unsigned short f2bf(float f) {
    union { float f; unsigned int u; } v; v.f = f;
    unsigned int u = v.u;
    u += 0x7fffu + ((u >> 16) & 1u);   // RNE
    return (unsigned short)(u >> 16);
}
__device__ inline float bf2f(unsigned short h) {
    union { unsigned int u; float f; } v; v.u = ((unsigned int)h) << 16;
    return v.f;
}
__device__ inline float rcpa(float x)  { return __builtin_amdgcn_rcpf(x); }
__device__ inline float exp2b(float x) { return __builtin_amdgcn_exp2f(x); }

// pack f32 pair -> bf16 hi pair + bf16 lo (residual) pair
__device__ inline void pk_pair(float a, float b, unsigned int& hi, unsigned int& lo) {
    unsigned int h;
    asm("v_cvt_pk_bf16_f32 %0, %1, %2" : "=v"(h) : "v"(a), "v"(b));
    union { unsigned int u; float f; } ua, ub;
    ua.u = h << 16; ub.u = h & 0xffff0000u;
    float la = a - ua.f, lb = b - ub.f;
    unsigned int l;
    asm("v_cvt_pk_bf16_f32 %0, %1, %2" : "=v"(l) : "v"(la), "v"(lb));
    hi = h; lo = l;
}

// ---- prep: pack weight A-fragments, split hi/lo bf16, pre-scaled by -log2e /
// -2log2e, with kappa k-relabeling: hardware k-slot (gk*8+e) holds W column
// j = (e>>2)*16 + gk*4 + (e&3). This makes MFMA C/D layout == B-frag layout.
__global__ void pack_frags(const float* __restrict__ Whh, const float* __restrict__ Wih,
                           unsigned short* __restrict__ WhFhi, unsigned short* __restrict__ WhFlo,
                           unsigned short* __restrict__ WiFhi, unsigned short* __restrict__ WiFlo)
{
    int tid = blockIdx.x * blockDim.x + threadIdx.x;
    const int NWH = L * NT * 64;          // 2304
    const int NWI = (L - 1) * NT * 64;    // 1920
    if (tid >= NWH + NWI) return;
    const float* src; unsigned short *dhi, *dlo; int tile, lane;
    if (tid < NWH) {
        int l = tid / (NT * 64); int r = tid % (NT * 64); tile = r / 64; lane = r % 64;
        src = Whh + l * 96 * H;
        dhi = WhFhi + tid * 8; dlo = WhFlo + tid * 8;
    } else {
        int t2 = tid - NWH;
        int l = t2 / (NT * 64); int r = t2 % (NT * 64); tile = r / 64; lane = r % 64;
        src = Wih + l * 96 * H;           // W_ih[l] feeds layer l+1
        dhi = WiFhi + t2 * 8; dlo = WiFlo + t2 * 8;
    }
    int row = tile * 16 + (lane & 15);
    int gk  = lane >> 4;
    float scale = (row < 64) ? -S1 : -2.0f * S1;
    unsigned short thi[8], tlo[8];
#pragma unroll
    for (int e = 0; e < 8; ++e) {
        int j = ((e >> 2) << 4) + (gk << 2) + (e & 3);   // kappa^-1
        float wv = scale * src[row * H + j];
        unsigned short h = f2bf(wv);
        thi[e] = h;
        tlo[e] = f2bf(wv - bf2f(h));
    }
    *(uint4*)dhi = *(const uint4*)thi;
    *(uint4*)dlo = *(const uint4*)tlo;
}

// ---- main: 8-wave layer ladder, ELASTIC producer-consumer sync (no per-tau
// barrier).  Each wave runs its own tau loop; sync is per-link LDS flags.
// This lets the two waves co-resident on a SIMD run in anti-phase, so one
// wave's MFMA burst overlaps the other's gate/pack VALU burst. ----
__global__ __launch_bounds__(TPB, 2) void gru_mfma(
    const float* __restrict__ x,          // [B][T]
    const float* __restrict__ Wih0,       // [96]
    const float* __restrict__ bih,        // [6][96]
    const float* __restrict__ bhh,        // [6][96]
    const unsigned short* __restrict__ WhFhi, const unsigned short* __restrict__ WhFlo,
    const unsigned short* __restrict__ WiFhi, const unsigned short* __restrict__ WiFlo,
    const float* __restrict__ Wk, const float* __restrict__ bk,
    const float* __restrict__ We, const float* __restrict__ be,
    const float* __restrict__ Wt, const float* __restrict__ bt,
    float* __restrict__ out, int B)
{
    // handoff slot per (layer 0..4, parity): grp0{hi 1K, lo 1K} grp1{hi 1K, lo 1K}.
    // row b = 64B; logical 16B-block c stored at column c ^ ((b>>1)&3).
    __shared__ unsigned char slot[5][2][4096];
    __shared__ float xt[T_LEN][BT];
    __shared__ float hpart[L][3][BT];
    // prodf[l]: last tau published into slot[l].  consf[l] (l=0..3): last tau
    // whose read of slot[l] completed (consumer = layer l+1).  consf[4]/[5]:
    // the two half-consumers (w5,w6) of slot[4].
    __shared__ int prodf[5];
    __shared__ int consf[6];

    const int tid  = threadIdx.x;
    const int wv   = tid >> 6;        // wave index
    const int lane = tid & 63;
    const int b    = lane & 15;       // batch col (MFMA N)
    const int g    = lane >> 4;       // k-group
    const int b0   = blockIdx.x * BT;

    // wave -> (layer, group-mask).  Waves land on SIMD (wv & 3); pairs are
    // {w0,w4} {w1,w5} {w2,w6} {w3,w7}.  Per-SIMD matrix load:
    //   S0:{L0,L1}  S1:{L2,L5.g0}  S2:{L3,L5.g1}  S3:{L4,idle}
    int layer, grmask;
    switch (wv) {
      case 0: layer = 0; grmask = 3; break;   // light: scalar input layer
      case 4: layer = 1; grmask = 3; break;
      case 1: layer = 2; grmask = 3; break;
      case 5: layer = 5; grmask = 1; break;   // half of L5
      case 2: layer = 3; grmask = 3; break;
      case 6: layer = 5; grmask = 2; break;   // other half of L5
      case 3: layer = 4; grmask = 3; break;
      default: layer = 5; grmask = 0; break;  // w7: idle helper
    }

    // stage x tile
    for (int idx = tid; idx < T_LEN * BT; idx += TPB) {
        int bb = idx / T_LEN, t = idx % T_LEN;
        xt[t][bb] = x[(b0 + bb) * T_LEN + t];
    }
    if (tid == 0) {
#pragma unroll
        for (int l = 0; l < 5; ++l) prodf[l] = -1;
        // init grants each producer its first two writes (into empty buffers):
        // gate for tau needs consf >= tau-1; first writes are tau = l, l+1.
        consf[0] = 0; consf[1] = 1; consf[2] = 2; consf[3] = 3;
        consf[4] = 4; consf[5] = 4;
    }

    // weight fragments for my layer, held in registers all 100 steps
    bf16x8 whh[NT], whl[NT], wih[NT], wil[NT];
    if (grmask) {
#pragma unroll
        for (int t6 = 0; t6 < NT; ++t6) {
            whh[t6] = ((const bf16x8*)WhFhi)[(layer * NT + t6) * 64 + lane];
            whl[t6] = ((const bf16x8*)WhFlo)[(layer * NT + t6) * 64 + lane];
        }
        if (layer > 0) {
#pragma unroll
            for (int t6 = 0; t6 < NT; ++t6) {
                wih[t6] = ((const bf16x8*)WiFhi)[((layer - 1) * NT + t6) * 64 + lane];
                wil[t6] = ((const bf16x8*)WiFlo)[((layer - 1) * NT + t6) * 64 + lane];
            }
        }
    }

    // pre-scaled biases in C/D layout (row = t6*16 + g*4 + r)
    f32x4 bc[4], bxn[2], bhn[2];
    if (grmask) {
        const int rb = g * 4;
#pragma unroll
        for (int t6 = 0; t6 < 4; ++t6)
#pragma unroll
            for (int r = 0; r < 4; ++r) {
                int row = t6 * 16 + rb + r;
                bc[t6][r] = -S1 * (bih[layer * 96 + row] + bhh[layer * 96 + row]);
            }
#pragma unroll
        for (int tt = 0; tt < 2; ++tt)
#pragma unroll
            for (int r = 0; r < 4; ++r) {
                int row = 64 + tt * 16 + rb + r;
                bxn[tt][r] = -2.0f * S1 * bih[layer * 96 + row];
                bhn[tt][r] = -2.0f * S1 * bhh[layer * 96 + row];
            }
        if (layer == 0) {
            // layer-0 wave never uses wih as frags: reuse for pre-scaled input weights
#pragma unroll
            for (int t6 = 0; t6 < NT; ++t6) {
                FragU u;
#pragma unroll
                for (int r = 0; r < 4; ++r) {
                    int row = t6 * 16 + rb + r;
                    float s = (row < 64) ? -S1 : -2.0f * S1;
                    u.f[r] = s * Wih0[row];
                }
                wih[t6] = u.s;
            }
        }
    }

    float hp[2][8];
#pragma unroll
    for (int gr = 0; gr < 2; ++gr)
#pragma unroll
        for (int i = 0; i < 8; ++i) hp[gr][i] = 0.0f;
    bf16x8 hfH[2] = {{0,0,0,0,0,0,0,0},{0,0,0,0,0,0,0,0}};
    bf16x8 hfL[2] = {{0,0,0,0,0,0,0,0},{0,0,0,0,0,0,0,0}};

    // unified slot offset (read & write identical): row b, logical block g,
    // XOR-swizzled by (b>>1)&3. Group gr adds gr*2048; lo half adds 1024.
    const int soff = b * 64 + ((g ^ ((b >> 1) & 3)) << 4);
    unsigned char* const sbase = (unsigned char*)slot;

    __syncthreads();

    if (grmask) {
        const int ci = (layer == 5) ? ((wv == 5) ? 4 : 5) : (layer - 1);
        for (int tau = layer; tau < layer + T_LEN; ++tau) {
            const int t = tau - layer;
            const int p = tau & 1, q = p ^ 1;
            f32x4 acc[2][4], accX[2][2], accH[2][2];

            // own-h terms first: pure register operands, independent of input;
            // biases are the MFMA C-init (accumulation is commutative)
#pragma unroll
            for (int gr = 0; gr < 2; ++gr)
                if (grmask & (1 << gr)) {
#pragma unroll
                    for (int t6 = 0; t6 < 4; ++t6) {
                        acc[gr][t6] = __builtin_amdgcn_mfma_f32_16x16x32_bf16(whh[t6], hfH[gr], bc[t6], 0, 0, 0);
                        acc[gr][t6] = __builtin_amdgcn_mfma_f32_16x16x32_bf16(whh[t6], hfL[gr], acc[gr][t6], 0, 0, 0);
                        acc[gr][t6] = __builtin_amdgcn_mfma_f32_16x16x32_bf16(whl[t6], hfH[gr], acc[gr][t6], 0, 0, 0);
                    }
#pragma unroll
                    for (int tt = 0; tt < 2; ++tt) {
                        accH[gr][tt] = __builtin_amdgcn_mfma_f32_16x16x32_bf16(whh[4 + tt], hfH[gr], bhn[tt], 0, 0, 0);
                        accH[gr][tt] = __builtin_amdgcn_mfma_f32_16x16x32_bf16(whh[4 + tt], hfL[gr], accH[gr][tt], 0, 0, 0);
                        accH[gr][tt] = __builtin_amdgcn_mfma_f32_16x16x32_bf16(whl[4 + tt], hfH[gr], accH[gr][tt], 0, 0, 0);
                    }
                }

            // input part
            if (layer == 0) {
#pragma unroll
                for (int gr = 0; gr < 2; ++gr) {
                    float xv = xt[t][gr * 16 + b];
#pragma unroll
                    for (int t6 = 0; t6 < 4; ++t6) {
                        FragU u; u.s = wih[t6];
#pragma unroll
                        for (int r = 0; r < 4; ++r)
                            acc[gr][t6][r] = fmaf(u.f[r], xv, acc[gr][t6][r]);
                    }
#pragma unroll
                    for (int tt = 0; tt < 2; ++tt) {
                        FragU u; u.s = wih[4 + tt];
#pragma unroll
                        for (int r = 0; r < 4; ++r)
                            accX[gr][tt][r] = fmaf(u.f[r], xv, bxn[tt][r]);
                    }
                }
            } else {
                // wait for producer, then read handoff
                while (__hip_atomic_load(&prodf[layer - 1], __ATOMIC_ACQUIRE,
                                         __HIP_MEMORY_SCOPE_WORKGROUP) < tau - 1)
                    __builtin_amdgcn_s_sleep(1);
                const unsigned char* ru = sbase + (((layer - 1) * 2 + q) << 12);
                bf16x8 iH[2], iL[2];
#pragma unroll
                for (int gr = 0; gr < 2; ++gr)
                    if (grmask & (1 << gr)) {
                        iH[gr] = *(const bf16x8*)(ru + gr * 2048 + soff);
                        iL[gr] = *(const bf16x8*)(ru + gr * 2048 + 1024 + soff);
                    }
#pragma unroll
                for (int gr = 0; gr < 2; ++gr)
                    if (grmask & (1 << gr)) {
#pragma unroll
                        for (int t6 = 0; t6 < 4; ++t6) {
                            acc[gr][t6] = __builtin_amdgcn_mfma_f32_16x16x32_bf16(wih[t6], iH[gr], acc[gr][t6], 0, 0, 0);
                            acc[gr][t6] = __builtin_amdgcn_mfma_f32_16x16x32_bf16(wih[t6], iL[gr], acc[gr][t6], 0, 0, 0);
                            acc[gr][t6] = __builtin_amdgcn_mfma_f32_16x16x32_bf16(wil[t6], iH[gr], acc[gr][t6], 0, 0, 0);
                        }
#pragma unroll
                        for (int tt = 0; tt < 2; ++tt) {
                            accX[gr][tt] = __builtin_amdgcn_mfma_f32_16x16x32_bf16(wih[4 + tt], iH[gr], bxn[tt], 0, 0, 0);
                            accX[gr][tt] = __builtin_amdgcn_mfma_f32_16x16x32_bf16(wih[4 + tt], iL[gr], accX[gr][tt], 0, 0, 0);
                            accX[gr][tt] = __builtin_amdgcn_mfma_f32_16x16x32_bf16(wil[4 + tt], iH[gr], accX[gr][tt], 0, 0, 0);
                        }
                    }
                // reads completed (MFMAs consumed them): release the buffer
                if (lane == 0)
                    __hip_atomic_store(&consf[ci], tau, __ATOMIC_RELEASE,
                                       __HIP_MEMORY_SCOPE_WORKGROUP);
            }

            // gates (pre-scaled): Er=e^-rpre, Ez=e^-zpre, En=e^-2npre
            // r = 1/(1+Er); n = (1-En)/(1+En); h = [n*Ez + hp] / (1+Ez)
            unsigned int hw[2][4], lw[2][4];
#pragma unroll
            for (int gr = 0; gr < 2; ++gr)
                if (grmask & (1 << gr)) {
                    float hnew[8];
#pragma unroll
                    for (int jj = 0; jj < 2; ++jj)
#pragma unroll
                        for (int r = 0; r < 4; ++r) {
                            float Er = exp2b(acc[gr][jj][r]);
                            float Ez = exp2b(acc[gr][2 + jj][r]);
                            float rg = rcpa(1.0f + Er);
                            float u  = fmaf(rg, accH[gr][jj][r], accX[gr][jj][r]);
                            float En = exp2b(u);
                            float en1 = 1.0f + En, ez1 = 1.0f + Ez;
                            float d   = rcpa(en1 * ez1);
                            float num = fmaf(hp[gr][jj * 4 + r], en1, (1.0f - En) * Ez);
                            hnew[jj * 4 + r] = num * d;
                        }
#pragma unroll
                    for (int i2 = 0; i2 < 8; ++i2) hp[gr][i2] = hnew[i2];

                    unsigned int h01, l01, h23, l23, h45, l45, h67, l67;
                    pk_pair(hnew[0], hnew[1], h01, l01);
                    pk_pair(hnew[2], hnew[3], h23, l23);
                    pk_pair(hnew[4], hnew[5], h45, l45);
                    pk_pair(hnew[6], hnew[7], h67, l67);
                    FragU Hu, Lu;
                    Hu.u[0] = h01; Hu.u[1] = h23; Hu.u[2] = h45; Hu.u[3] = h67;
                    Lu.u[0] = l01; Lu.u[1] = l23; Lu.u[2] = l45; Lu.u[3] = l67;
                    hfH[gr] = Hu.s; hfL[gr] = Lu.s;
                    hw[gr][0] = h01; hw[gr][1] = h23; hw[gr][2] = h45; hw[gr][3] = h67;
                    lw[gr][0] = l01; lw[gr][1] = l23; lw[gr][2] = l45; lw[gr][3] = l67;
                }

            // write-out, gated on the consumer having freed this buffer
            if (layer < L - 1) {
                const int need = tau - 1;
                if (layer == 4) {
                    while (__hip_atomic_load(&consf[4], __ATOMIC_ACQUIRE, __HIP_MEMORY_SCOPE_WORKGROUP) < need ||
                           __hip_atomic_load(&consf[5], __ATOMIC_ACQUIRE, __HIP_MEMORY_SCOPE_WORKGROUP) < need)
                        __builtin_amdgcn_s_sleep(1);
                } else {
                    while (__hip_atomic_load(&consf[layer], __ATOMIC_ACQUIRE, __HIP_MEMORY_SCOPE_WORKGROUP) < need)
                        __builtin_amdgcn_s_sleep(1);
                }
                unsigned char* wp0 = sbase + ((layer * 2 + p) << 12);
#pragma unroll
                for (int gr = 0; gr < 2; ++gr) {
                    unsigned char* wp = wp0 + gr * 2048;
                    *(uint4*)(wp + soff)        = make_uint4(hw[gr][0], hw[gr][1], hw[gr][2], hw[gr][3]);
                    *(uint4*)(wp + 1024 + soff) = make_uint4(lw[gr][0], lw[gr][1], lw[gr][2], lw[gr][3]);
                }
                if (lane == 0)
                    __hip_atomic_store(&prodf[layer], tau, __ATOMIC_RELEASE,
                                       __HIP_MEMORY_SCOPE_WORKGROUP);
            }
        }
    }

    // heads: per-(layer,group) partial over 32 hidden units, then cross-wave reduce
    {
        const int rb = g * 4;
#pragma unroll
        for (int hd = 0; hd < 3; ++hd) {
            const float* W = (hd == 0) ? Wk : (hd == 1) ? We : Wt;
#pragma unroll
            for (int gr = 0; gr < 2; ++gr)
                if (grmask & (1 << gr)) {
                    float s = 0.0f;
#pragma unroll
                    for (int jj = 0; jj < 2; ++jj)
#pragma unroll
                        for (int r = 0; r < 4; ++r)
                            s = fmaf(W[layer * H + jj * 16 + rb + r], hp[gr][jj * 4 + r], s);
                    s += __shfl_xor(s, 16, 64);
                    s += __shfl_xor(s, 32, 64);
                    if (g == 0) hpart[layer][hd][gr * 16 + b] = s;
                }
        }
        __syncthreads();
        if (wv < 3 && lane < BT) {
            int bb = lane;
            float s = (wv == 0) ? bk[0] : (wv == 1) ? be[0] : bt[0];
#pragma unroll
            for (int l = 0; l < L; ++l) s += hpart[l][wv][bb];
            out[wv * B + b0 + bb] = s;
        }
    }
}

extern "C" void kernel_launch(void* const* d_in, const int* in_sizes, int n_in,
                              void* d_out, int out_size, void* d_ws, size_t ws_size,
                              hipStream_t stream)
{
    const float* x    = (const float*)d_in[0];
    const float* Wih0 = (const float*)d_in[1];
    const float* Wih  = (const float*)d_in[2];
    const float* Whh  = (const float*)d_in[3];
    const float* bih  = (const float*)d_in[4];
    const float* bhh  = (const float*)d_in[5];
    const float* Wk   = (const float*)d_in[6];
    const float* bk   = (const float*)d_in[7];
    const float* We   = (const float*)d_in[8];
    const float* be   = (const float*)d_in[9];
    const float* Wt   = (const float*)d_in[10];
    const float* bt   = (const float*)d_in[11];
    float* out = (float*)d_out;

    const int B = in_sizes[0] / T_LEN;   // 16384

    unsigned short* WhFhi = (unsigned short*)d_ws;        // 6*6*64*8 bf16
    unsigned short* WhFlo = WhFhi + L * NT * 64 * 8;
    unsigned short* WiFhi = WhFlo + L * NT * 64 * 8;      // 5*6*64*8 bf16
    unsigned short* WiFlo = WiFhi + (L - 1) * NT * 64 * 8;

    const int nPack = (L * NT * 64) + ((L - 1) * NT * 64);  // 4224
    pack_frags<<<(nPack + 255) / 256, 256, 0, stream>>>(Whh, Wih, WhFhi, WhFlo, WiFhi, WiFlo);
    gru_mfma<<<B / BT, TPB, 0, stream>>>(x, Wih0, bih, bhh, WhFhi, WhFlo, WiFhi, WiFlo,
                                         Wk, bk, We, be, Wt, bt, out, B);
}

// Round 3
// 465.517 us; speedup vs baseline: 1.2458x; 1.2458x over previous
//
#include <hip/hip_runtime.h>

#define T_LEN 100
#define H 32
#define L 6
#define NT 6          // 96 gate rows / 16
#define TPB 512       // 8 waves: SIMD s hosts waves {s, s+4}
#define BT 32         // two independent 16-batch groups per block
#define NK (T_LEN + 7) // 107 intervals: skews d=[0,1,3,4,5,6] + B-phase epilogue
#define S1 1.44269504088896f   // log2(e)

typedef float f32x4  __attribute__((ext_vector_type(4)));
typedef short bf16x8 __attribute__((ext_vector_type(8)));

union FragU { bf16x8 s; f32x4 f; unsigned int u[4]; };

__device__ inline unsigned short f2bf(float f) {
    union { float f; unsigned int u; } v; v.f = f;
    unsigned int u = v.u;
    u += 0x7fffu + ((u >> 16) & 1u);   // RNE
    return (unsigned short)(u >> 16);
}
__device__ inline float bf2f(unsigned short h) {
    union { unsigned int u; float f; } v; v.u = ((unsigned int)h) << 16;
    return v.f;
}
__device__ inline float rcpa(float x)  { return __builtin_amdgcn_rcpf(x); }
__device__ inline float exp2b(float x) { return __builtin_amdgcn_exp2f(x); }

// pack f32 pair -> bf16 hi pair + bf16 lo (residual) pair
__device__ inline void pk_pair(float a, float b, unsigned int& hi, unsigned int& lo) {
    unsigned int h;
    asm("v_cvt_pk_bf16_f32 %0, %1, %2" : "=v"(h) : "v"(a), "v"(b));
    union { unsigned int u; float f; } ua, ub;
    ua.u = h << 16; ub.u = h & 0xffff0000u;
    float la = a - ua.f, lb = b - ub.f;
    unsigned int l;
    asm("v_cvt_pk_bf16_f32 %0, %1, %2" : "=v"(l) : "v"(la), "v"(lb));
    hi = h; lo = l;
}

// ---- prep: pack weight A-fragments, split hi/lo bf16, pre-scaled by -log2e /
// -2log2e, with kappa k-relabeling: hardware k-slot (gk*8+e) holds W column
// j = (e>>2)*16 + gk*4 + (e&3). This makes MFMA C/D layout == B-frag layout.
__global__ void pack_frags(const float* __restrict__ Whh, const float* __restrict__ Wih,
                           unsigned short* __restrict__ WhFhi, unsigned short* __restrict__ WhFlo,
                           unsigned short* __restrict__ WiFhi, unsigned short* __restrict__ WiFlo)
{
    int tid = blockIdx.x * blockDim.x + threadIdx.x;
    const int NWH = L * NT * 64;          // 2304
    const int NWI = (L - 1) * NT * 64;    // 1920
    if (tid >= NWH + NWI) return;
    const float* src; unsigned short *dhi, *dlo; int tile, lane;
    if (tid < NWH) {
        int l = tid / (NT * 64); int r = tid % (NT * 64); tile = r / 64; lane = r % 64;
        src = Whh + l * 96 * H;
        dhi = WhFhi + tid * 8; dlo = WhFlo + tid * 8;
    } else {
        int t2 = tid - NWH;
        int l = t2 / (NT * 64); int r = t2 % (NT * 64); tile = r / 64; lane = r % 64;
        src = Wih + l * 96 * H;           // W_ih[l] feeds layer l+1
        dhi = WiFhi + t2 * 8; dlo = WiFlo + t2 * 8;
    }
    int row = tile * 16 + (lane & 15);
    int gk  = lane >> 4;
    float scale = (row < 64) ? -S1 : -2.0f * S1;
    unsigned short thi[8], tlo[8];
#pragma unroll
    for (int e = 0; e < 8; ++e) {
        int j = ((e >> 2) << 4) + (gk << 2) + (e & 3);   // kappa^-1
        float wv = scale * src[row * H + j];
        unsigned short h = f2bf(wv);
        thi[e] = h;
        tlo[e] = f2bf(wv - bf2f(h));
    }
    *(uint4*)dhi = *(const uint4*)thi;
    *(uint4*)dlo = *(const uint4*)tlo;
}

// ---- main: 8-wave layer ladder, barrier-synced, ANTI-PHASE scheduling.
// A-waves: [MFMA(t); gates(t)] per interval.  B-waves: [gates(t-1); MFMA(t)],
// accumulators live across one barrier.  SIMD pairs {w,w+4} get opposite
// phases so one wave's MFMA burst overlaps the partner's gate VALU burst.
// Handoff skews d=[0,1,3,4,5,6]; slot parity keyed on t&1 both sides. ----
__global__ __launch_bounds__(TPB, 2) void gru_mfma(
    const float* __restrict__ x,          // [B][T]
    const float* __restrict__ Wih0,       // [96]
    const float* __restrict__ bih,        // [6][96]
    const float* __restrict__ bhh,        // [6][96]
    const unsigned short* __restrict__ WhFhi, const unsigned short* __restrict__ WhFlo,
    const unsigned short* __restrict__ WiFhi, const unsigned short* __restrict__ WiFlo,
    const float* __restrict__ Wk, const float* __restrict__ bk,
    const float* __restrict__ We, const float* __restrict__ be,
    const float* __restrict__ Wt, const float* __restrict__ bt,
    float* __restrict__ out, int B)
{
    // handoff slot per (layer 0..4, t&1): grp0{hi 1K, lo 1K} grp1{hi 1K, lo 1K}.
    // row b = 64B; logical 16B-block c stored at column c ^ ((b>>1)&3).
    __shared__ unsigned char slot[5][2][4096];
    __shared__ float xt[T_LEN][BT];
    __shared__ float hpart[L][3][BT];

    const int tid  = threadIdx.x;
    const int wv   = tid >> 6;        // wave index
    const int lane = tid & 63;
    const int b    = lane & 15;       // batch col (MFMA N)
    const int g    = lane >> 4;       // k-group
    const int b0   = blockIdx.x * BT;

    // wave -> (layer, group-mask, phase, skew).  SIMD pairs {w0,w4} {w1,w5}
    // {w2,w6} {w3,w7} carry {L0,L1} {L2,L5a} {L3,L5b} {L4,idle}; the second
    // wave of each pair runs phase B (gates-then-MFMA) for anti-phase overlap.
    int layer, grmask, phB, dsk;
    switch (wv) {
      case 0: layer = 0; grmask = 3; phB = 0; dsk = 0; break;  // light scalar layer
      case 4: layer = 1; grmask = 3; phB = 1; dsk = 1; break;
      case 1: layer = 2; grmask = 3; phB = 0; dsk = 3; break;
      case 5: layer = 5; grmask = 1; phB = 1; dsk = 6; break;  // half of L5
      case 2: layer = 3; grmask = 3; phB = 0; dsk = 4; break;
      case 6: layer = 5; grmask = 2; phB = 1; dsk = 6; break;  // other half of L5
      case 3: layer = 4; grmask = 3; phB = 0; dsk = 5; break;
      default: layer = 5; grmask = 0; phB = 0; dsk = 0; break; // w7: barrier helper
    }

    // stage x tile
    for (int idx = tid; idx < T_LEN * BT; idx += TPB) {
        int bb = idx / T_LEN, t = idx % T_LEN;
        xt[t][bb] = x[(b0 + bb) * T_LEN + t];
    }

    // weight fragments for my layer, held in registers all 100 steps
    bf16x8 whh[NT], whl[NT], wih[NT], wil[NT];
    if (grmask) {
#pragma unroll
        for (int t6 = 0; t6 < NT; ++t6) {
            whh[t6] = ((const bf16x8*)WhFhi)[(layer * NT + t6) * 64 + lane];
            whl[t6] = ((const bf16x8*)WhFlo)[(layer * NT + t6) * 64 + lane];
        }
        if (layer > 0) {
#pragma unroll
            for (int t6 = 0; t6 < NT; ++t6) {
                wih[t6] = ((const bf16x8*)WiFhi)[((layer - 1) * NT + t6) * 64 + lane];
                wil[t6] = ((const bf16x8*)WiFlo)[((layer - 1) * NT + t6) * 64 + lane];
            }
        }
    }

    // pre-scaled biases in C/D layout (row = t6*16 + g*4 + r)
    f32x4 bc[4], bxn[2], bhn[2];
    if (grmask) {
        const int rb = g * 4;
#pragma unroll
        for (int t6 = 0; t6 < 4; ++t6)
#pragma unroll
            for (int r = 0; r < 4; ++r) {
                int row = t6 * 16 + rb + r;
                bc[t6][r] = -S1 * (bih[layer * 96 + row] + bhh[layer * 96 + row]);
            }
#pragma unroll
        for (int tt = 0; tt < 2; ++tt)
#pragma unroll
            for (int r = 0; r < 4; ++r) {
                int row = 64 + tt * 16 + rb + r;
                bxn[tt][r] = -2.0f * S1 * bih[layer * 96 + row];
                bhn[tt][r] = -2.0f * S1 * bhh[layer * 96 + row];
            }
        if (layer == 0) {
            // layer-0 wave never uses wih as frags: reuse for pre-scaled input weights
#pragma unroll
            for (int t6 = 0; t6 < NT; ++t6) {
                FragU u;
#pragma unroll
                for (int r = 0; r < 4; ++r) {
                    int row = t6 * 16 + rb + r;
                    float s = (row < 64) ? -S1 : -2.0f * S1;
                    u.f[r] = s * Wih0[row];
                }
                wih[t6] = u.s;
            }
        }
    }

    float hp[2][8];
#pragma unroll
    for (int gr = 0; gr < 2; ++gr)
#pragma unroll
        for (int i = 0; i < 8; ++i) hp[gr][i] = 0.0f;
    bf16x8 hfH[2] = {{0,0,0,0,0,0,0,0},{0,0,0,0,0,0,0,0}};
    bf16x8 hfL[2] = {{0,0,0,0,0,0,0,0},{0,0,0,0,0,0,0,0}};

    // accumulators persist across barriers for B-phase waves
    f32x4 acc[2][4], accX[2][2], accH[2][2];

    // unified slot offset (read & write identical): row b, logical block g,
    // XOR-swizzled by (b>>1)&3. Group gr adds gr*2048; lo half adds 1024.
    const int soff = b * 64 + ((g ^ ((b >> 1) & 3)) << 4);
    unsigned char* const sbase = (unsigned char*)slot;

    auto do_mfma = [&](int t) {
        const int q = t & 1;
        // issue handoff LDS reads first; latency hides under own-h MFMAs
        bf16x8 iH[2], iL[2];
        if (layer > 0) {
            const unsigned char* ru = sbase + (((layer - 1) * 2 + q) << 12);
#pragma unroll
            for (int gr = 0; gr < 2; ++gr)
                if (grmask & (1 << gr)) {
                    iH[gr] = *(const bf16x8*)(ru + gr * 2048 + soff);
                    iL[gr] = *(const bf16x8*)(ru + gr * 2048 + 1024 + soff);
                }
        }
        // own-h terms: pure register operands; biases are the MFMA C-init
#pragma unroll
        for (int gr = 0; gr < 2; ++gr)
            if (grmask & (1 << gr)) {
#pragma unroll
                for (int t6 = 0; t6 < 4; ++t6) {
                    acc[gr][t6] = __builtin_amdgcn_mfma_f32_16x16x32_bf16(whh[t6], hfH[gr], bc[t6], 0, 0, 0);
                    acc[gr][t6] = __builtin_amdgcn_mfma_f32_16x16x32_bf16(whh[t6], hfL[gr], acc[gr][t6], 0, 0, 0);
                    acc[gr][t6] = __builtin_amdgcn_mfma_f32_16x16x32_bf16(whl[t6], hfH[gr], acc[gr][t6], 0, 0, 0);
                }
#pragma unroll
                for (int tt = 0; tt < 2; ++tt) {
                    accH[gr][tt] = __builtin_amdgcn_mfma_f32_16x16x32_bf16(whh[4 + tt], hfH[gr], bhn[tt], 0, 0, 0);
                    accH[gr][tt] = __builtin_amdgcn_mfma_f32_16x16x32_bf16(whh[4 + tt], hfL[gr], accH[gr][tt], 0, 0, 0);
                    accH[gr][tt] = __builtin_amdgcn_mfma_f32_16x16x32_bf16(whl[4 + tt], hfH[gr], accH[gr][tt], 0, 0, 0);
                }
            }
        // input part
        if (layer == 0) {
#pragma unroll
            for (int gr = 0; gr < 2; ++gr)
                if (grmask & (1 << gr)) {
                    float xv = xt[t][gr * 16 + b];
#pragma unroll
                    for (int t6 = 0; t6 < 4; ++t6) {
                        FragU u; u.s = wih[t6];
#pragma unroll
                        for (int r = 0; r < 4; ++r)
                            acc[gr][t6][r] = fmaf(u.f[r], xv, acc[gr][t6][r]);
                    }
#pragma unroll
                    for (int tt = 0; tt < 2; ++tt) {
                        FragU u; u.s = wih[4 + tt];
#pragma unroll
                        for (int r = 0; r < 4; ++r)
                            accX[gr][tt][r] = fmaf(u.f[r], xv, bxn[tt][r]);
                    }
                }
        } else {
#pragma unroll
            for (int gr = 0; gr < 2; ++gr)
                if (grmask & (1 << gr)) {
#pragma unroll
                    for (int t6 = 0; t6 < 4; ++t6) {
                        acc[gr][t6] = __builtin_amdgcn_mfma_f32_16x16x32_bf16(wih[t6], iH[gr], acc[gr][t6], 0, 0, 0);
                        acc[gr][t6] = __builtin_amdgcn_mfma_f32_16x16x32_bf16(wih[t6], iL[gr], acc[gr][t6], 0, 0, 0);
                        acc[gr][t6] = __builtin_amdgcn_mfma_f32_16x16x32_bf16(wil[t6], iH[gr], acc[gr][t6], 0, 0, 0);
                    }
#pragma unroll
                    for (int tt = 0; tt < 2; ++tt) {
                        accX[gr][tt] = __builtin_amdgcn_mfma_f32_16x16x32_bf16(wih[4 + tt], iH[gr], bxn[tt], 0, 0, 0);
                        accX[gr][tt] = __builtin_amdgcn_mfma_f32_16x16x32_bf16(wih[4 + tt], iL[gr], accX[gr][tt], 0, 0, 0);
                        accX[gr][tt] = __builtin_amdgcn_mfma_f32_16x16x32_bf16(wil[4 + tt], iH[gr], accX[gr][tt], 0, 0, 0);
                    }
                }
        }
    };

    auto do_gates = [&](int t) {
        const int p = t & 1;
        // gates (pre-scaled): Er=e^-rpre, Ez=e^-zpre, En=e^-2npre
        // r = 1/(1+Er); n = (1-En)/(1+En); h = [n*Ez + hp] / (1+Ez)
#pragma unroll
        for (int gr = 0; gr < 2; ++gr)
            if (grmask & (1 << gr)) {
                float hnew[8];
#pragma unroll
                for (int jj = 0; jj < 2; ++jj)
#pragma unroll
                    for (int r = 0; r < 4; ++r) {
                        float Er = exp2b(acc[gr][jj][r]);
                        float Ez = exp2b(acc[gr][2 + jj][r]);
                        float rg = rcpa(1.0f + Er);
                        float u  = fmaf(rg, accH[gr][jj][r], accX[gr][jj][r]);
                        float En = exp2b(u);
                        float en1 = 1.0f + En, ez1 = 1.0f + Ez;
                        float d   = rcpa(en1 * ez1);
                        float num = fmaf(hp[gr][jj * 4 + r], en1, (1.0f - En) * Ez);
                        hnew[jj * 4 + r] = num * d;
                    }
#pragma unroll
                for (int i2 = 0; i2 < 8; ++i2) hp[gr][i2] = hnew[i2];

                unsigned int h01, l01, h23, l23, h45, l45, h67, l67;
                pk_pair(hnew[0], hnew[1], h01, l01);
                pk_pair(hnew[2], hnew[3], h23, l23);
                pk_pair(hnew[4], hnew[5], h45, l45);
                pk_pair(hnew[6], hnew[7], h67, l67);
                FragU Hu, Lu;
                Hu.u[0] = h01; Hu.u[1] = h23; Hu.u[2] = h45; Hu.u[3] = h67;
                Lu.u[0] = l01; Lu.u[1] = l23; Lu.u[2] = l45; Lu.u[3] = l67;
                hfH[gr] = Hu.s; hfL[gr] = Lu.s;
                if (layer < L - 1) {
                    unsigned char* wp = sbase + ((layer * 2 + p) << 12) + gr * 2048;
                    *(uint4*)(wp + soff)        = make_uint4(h01, h23, h45, h67);
                    *(uint4*)(wp + 1024 + soff) = make_uint4(l01, l23, l45, l67);
                }
            }
    };

    __syncthreads();

    for (int k = 0; k < NK; ++k) {
        if (grmask) {
            if (!phB) {
                int t = k - dsk;
                if (0 <= t && t < T_LEN) { do_mfma(t); do_gates(t); }
            } else {
                int tp = k - dsk - 1;
                if (0 <= tp && tp < T_LEN) do_gates(tp);   // finish prev step
                int t = k - dsk;
                if (0 <= t && t < T_LEN) do_mfma(t);       // start current step
            }
        }
        __syncthreads();
    }

    // heads: per-(layer,group) partial over 32 hidden units, then cross-wave reduce
    {
        const int rb = g * 4;
#pragma unroll
        for (int hd = 0; hd < 3; ++hd) {
            const float* W = (hd == 0) ? Wk : (hd == 1) ? We : Wt;
#pragma unroll
            for (int gr = 0; gr < 2; ++gr)
                if (grmask & (1 << gr)) {
                    float s = 0.0f;
#pragma unroll
                    for (int jj = 0; jj < 2; ++jj)
#pragma unroll
                        for (int r = 0; r < 4; ++r)
                            s = fmaf(W[layer * H + jj * 16 + rb + r], hp[gr][jj * 4 + r], s);
                    s += __shfl_xor(s, 16, 64);
                    s += __shfl_xor(s, 32, 64);
                    if (g == 0) hpart[layer][hd][gr * 16 + b] = s;
                }
        }
        __syncthreads();
        if (wv < 3 && lane < BT) {
            int bb = lane;
            float s = (wv == 0) ? bk[0] : (wv == 1) ? be[0] : bt[0];
#pragma unroll
            for (int l = 0; l < L; ++l) s += hpart[l][wv][bb];
            out[wv * B + b0 + bb] = s;
        }
    }
}

extern "C" void kernel_launch(void* const* d_in, const int* in_sizes, int n_in,
                              void* d_out, int out_size, void* d_ws, size_t ws_size,
                              hipStream_t stream)
{
    const float* x    = (const float*)d_in[0];
    const float* Wih0 = (const float*)d_in[1];
    const float* Wih  = (const float*)d_in[2];
    const float* Whh  = (const float*)d_in[3];
    const float* bih  = (const float*)d_in[4];
    const float* bhh  = (const float*)d_in[5];
    const float* Wk   = (const float*)d_in[6];
    const float* bk   = (const float*)d_in[7];
    const float* We   = (const float*)d_in[8];
    const float* be   = (const float*)d_in[9];
    const float* Wt   = (const float*)d_in[10];
    const float* bt   = (const float*)d_in[11];
    float* out = (float*)d_out;

    const int B = in_sizes[0] / T_LEN;   // 16384

    unsigned short* WhFhi = (unsigned short*)d_ws;        // 6*6*64*8 bf16
    unsigned short* WhFlo = WhFhi + L * NT * 64 * 8;
    unsigned short* WiFhi = WhFlo + L * NT * 64 * 8;      // 5*6*64*8 bf16
    unsigned short* WiFlo = WiFhi + (L - 1) * NT * 64 * 8;

    const int nPack = (L * NT * 64) + ((L - 1) * NT * 64);  // 4224
    pack_frags<<<(nPack + 255) / 256, 256, 0, stream>>>(Whh, Wih, WhFhi, WhFlo, WiFhi, WiFlo);
    gru_mfma<<<B / BT, TPB, 0, stream>>>(x, Wih0, bih, bhh, WhFhi, WhFlo, WiFhi, WiFlo,
                                         Wk, bk, We, be, Wt, bt, out, B);
}

// Round 4
// 362.851 us; speedup vs baseline: 1.5983x; 1.2829x over previous
//
#include <hip/hip_runtime.h>

#define T_LEN 100
#define H 32
#define L 6
#define NT 6          // 96 gate rows / 16
#define TPB 512       // 8 waves: SIMD s hosts waves {s, s+4}
#define BT 32         // two independent 16-batch groups per block
#define NPAIR 50      // two timesteps per barrier interval
#define NK (NPAIR + L - 1)   // 55 intervals, layer skew d = layer
#define S1 1.44269504088896f   // log2(e)

typedef float f32x4  __attribute__((ext_vector_type(4)));
typedef short bf16x8 __attribute__((ext_vector_type(8)));

union FragU { bf16x8 s; f32x4 f; unsigned int u[4]; };

__device__ inline unsigned short f2bf(float f) {
    union { float f; unsigned int u; } v; v.f = f;
    unsigned int u = v.u;
    u += 0x7fffu + ((u >> 16) & 1u);   // RNE
    return (unsigned short)(u >> 16);
}
__device__ inline float bf2f(unsigned short h) {
    union { unsigned int u; float f; } v; v.u = ((unsigned int)h) << 16;
    return v.f;
}
__device__ inline float rcpa(float x)  { return __builtin_amdgcn_rcpf(x); }
__device__ inline float exp2b(float x) { return __builtin_amdgcn_exp2f(x); }

// pack f32 pair -> bf16 hi pair + bf16 lo (residual) pair
__device__ inline void pk_pair(float a, float b, unsigned int& hi, unsigned int& lo) {
    unsigned int h;
    asm("v_cvt_pk_bf16_f32 %0, %1, %2" : "=v"(h) : "v"(a), "v"(b));
    union { unsigned int u; float f; } ua, ub;
    ua.u = h << 16; ub.u = h & 0xffff0000u;
    float la = a - ua.f, lb = b - ub.f;
    unsigned int l;
    asm("v_cvt_pk_bf16_f32 %0, %1, %2" : "=v"(l) : "v"(la), "v"(lb));
    hi = h; lo = l;
}

// ---- prep: pack weight A-fragments, split hi/lo bf16, pre-scaled by -log2e /
// -2log2e, with kappa k-relabeling: hardware k-slot (gk*8+e) holds W column
// j = (e>>2)*16 + gk*4 + (e&3). This makes MFMA C/D layout == B-frag layout.
__global__ void pack_frags(const float* __restrict__ Whh, const float* __restrict__ Wih,
                           unsigned short* __restrict__ WhFhi, unsigned short* __restrict__ WhFlo,
                           unsigned short* __restrict__ WiFhi, unsigned short* __restrict__ WiFlo)
{
    int tid = blockIdx.x * blockDim.x + threadIdx.x;
    const int NWH = L * NT * 64;          // 2304
    const int NWI = (L - 1) * NT * 64;    // 1920
    if (tid >= NWH + NWI) return;
    const float* src; unsigned short *dhi, *dlo; int tile, lane;
    if (tid < NWH) {
        int l = tid / (NT * 64); int r = tid % (NT * 64); tile = r / 64; lane = r % 64;
        src = Whh + l * 96 * H;
        dhi = WhFhi + tid * 8; dlo = WhFlo + tid * 8;
    } else {
        int t2 = tid - NWH;
        int l = t2 / (NT * 64); int r = t2 % (NT * 64); tile = r / 64; lane = r % 64;
        src = Wih + l * 96 * H;           // W_ih[l] feeds layer l+1
        dhi = WiFhi + t2 * 8; dlo = WiFlo + t2 * 8;
    }
    int row = tile * 16 + (lane & 15);
    int gk  = lane >> 4;
    float scale = (row < 64) ? -S1 : -2.0f * S1;
    unsigned short thi[8], tlo[8];
#pragma unroll
    for (int e = 0; e < 8; ++e) {
        int j = ((e >> 2) << 4) + (gk << 2) + (e & 3);   // kappa^-1
        float wv = scale * src[row * H + j];
        unsigned short h = f2bf(wv);
        thi[e] = h;
        tlo[e] = f2bf(wv - bf2f(h));
    }
    *(uint4*)dhi = *(const uint4*)thi;
    *(uint4*)dlo = *(const uint4*)tlo;
}

// ---- main: 8-wave layer ladder, barrier-synced, TWO steps per interval.
// VALU-balanced wave map: SIMD pairs {L0,L1a} {L2,L1b} {L3,L5a} {L4,L5b},
// each ~1.5 layer-equivalents of gate (trans-pipe) work.  55 barriers
// instead of 107 halves per-interval fixed overhead (drain, spread, ramp).
__global__ __launch_bounds__(TPB, 2) void gru_mfma(
    const float* __restrict__ x,          // [B][T]
    const float* __restrict__ Wih0,       // [96]
    const float* __restrict__ bih,        // [6][96]
    const float* __restrict__ bhh,        // [6][96]
    const unsigned short* __restrict__ WhFhi, const unsigned short* __restrict__ WhFlo,
    const unsigned short* __restrict__ WiFhi, const unsigned short* __restrict__ WiFlo,
    const float* __restrict__ Wk, const float* __restrict__ bk,
    const float* __restrict__ We, const float* __restrict__ be,
    const float* __restrict__ Wt, const float* __restrict__ bt,
    float* __restrict__ out, int B)
{
    // handoff slot per (layer 0..4, interval parity, step 0/1):
    // grp0{hi 1K, lo 1K} grp1{hi 1K, lo 1K}.  row b = 64B; logical 16B-block
    // c stored at column c ^ ((b>>1)&3).
    __shared__ unsigned char slot[5][2][2][4096];
    __shared__ float xt[T_LEN][BT];
    __shared__ float hpart[L][3][BT];

    const int tid  = threadIdx.x;
    const int wv   = tid >> 6;        // wave index
    const int lane = tid & 63;
    const int b    = lane & 15;       // batch col (MFMA N)
    const int g    = lane >> 4;       // k-group
    const int b0   = blockIdx.x * BT;

    // wave -> (layer, group-mask).  SIMD pairs {w0,w4} {w1,w5} {w2,w6}
    // {w3,w7}.  L1 and L5 are split in half (one 16-batch group each) so
    // every SIMD carries ~1.5 layers of gate VALU/trans work:
    //   S0:{L0, L1.g0}  S1:{L2, L1.g1}  S2:{L3, L5.g0}  S3:{L4, L5.g1}
    int layer, grmask;
    switch (wv) {
      case 0: layer = 0; grmask = 3; break;   // light scalar-input layer
      case 4: layer = 1; grmask = 1; break;
      case 1: layer = 2; grmask = 3; break;
      case 5: layer = 1; grmask = 2; break;
      case 2: layer = 3; grmask = 3; break;
      case 6: layer = 5; grmask = 1; break;
      case 3: layer = 4; grmask = 3; break;
      default: layer = 5; grmask = 2; break;  // w7
    }

    // stage x tile
    for (int idx = tid; idx < T_LEN * BT; idx += TPB) {
        int bb = idx / T_LEN, t = idx % T_LEN;
        xt[t][bb] = x[(b0 + bb) * T_LEN + t];
    }

    // weight fragments for my layer, held in registers all 100 steps
    bf16x8 whh[NT], whl[NT], wih[NT], wil[NT];
#pragma unroll
    for (int t6 = 0; t6 < NT; ++t6) {
        whh[t6] = ((const bf16x8*)WhFhi)[(layer * NT + t6) * 64 + lane];
        whl[t6] = ((const bf16x8*)WhFlo)[(layer * NT + t6) * 64 + lane];
    }
    if (layer > 0) {
#pragma unroll
        for (int t6 = 0; t6 < NT; ++t6) {
            wih[t6] = ((const bf16x8*)WiFhi)[((layer - 1) * NT + t6) * 64 + lane];
            wil[t6] = ((const bf16x8*)WiFlo)[((layer - 1) * NT + t6) * 64 + lane];
        }
    }

    // pre-scaled biases in C/D layout (row = t6*16 + g*4 + r)
    f32x4 bc[4], bxn[2], bhn[2];
    {
        const int rb = g * 4;
#pragma unroll
        for (int t6 = 0; t6 < 4; ++t6)
#pragma unroll
            for (int r = 0; r < 4; ++r) {
                int row = t6 * 16 + rb + r;
                bc[t6][r] = -S1 * (bih[layer * 96 + row] + bhh[layer * 96 + row]);
            }
#pragma unroll
        for (int tt = 0; tt < 2; ++tt)
#pragma unroll
            for (int r = 0; r < 4; ++r) {
                int row = 64 + tt * 16 + rb + r;
                bxn[tt][r] = -2.0f * S1 * bih[layer * 96 + row];
                bhn[tt][r] = -2.0f * S1 * bhh[layer * 96 + row];
            }
        if (layer == 0) {
            // layer-0 wave never uses wih as frags: reuse for pre-scaled input weights
#pragma unroll
            for (int t6 = 0; t6 < NT; ++t6) {
                FragU u;
#pragma unroll
                for (int r = 0; r < 4; ++r) {
                    int row = t6 * 16 + rb + r;
                    float s = (row < 64) ? -S1 : -2.0f * S1;
                    u.f[r] = s * Wih0[row];
                }
                wih[t6] = u.s;
            }
        }
    }

    float hp[2][8];
#pragma unroll
    for (int gr = 0; gr < 2; ++gr)
#pragma unroll
        for (int i = 0; i < 8; ++i) hp[gr][i] = 0.0f;
    bf16x8 hfH[2] = {{0,0,0,0,0,0,0,0},{0,0,0,0,0,0,0,0}};
    bf16x8 hfL[2] = {{0,0,0,0,0,0,0,0},{0,0,0,0,0,0,0,0}};

    // unified slot offset (read & write identical): row b, logical block g,
    // XOR-swizzled by (b>>1)&3. Group gr adds gr*2048; lo half adds 1024.
    const int soff = b * 64 + ((g ^ ((b >> 1) & 3)) << 4);
    unsigned char* const sbase = (unsigned char*)slot;

    // one GRU step: MFMA part + gates.  rq = producer parity to read,
    // wp = parity to write, st = step slot (0/1) within the pair.
    auto do_step = [&](int t, int rq, int wp, int st) {
        f32x4 acc[2][4], accX[2][2], accH[2][2];
        // issue handoff LDS reads first; latency hides under own-h MFMAs
        bf16x8 iH[2], iL[2];
        if (layer > 0) {
            const unsigned char* ru = sbase + (((layer - 1) * 4 + rq * 2 + st) << 12);
#pragma unroll
            for (int gr = 0; gr < 2; ++gr)
                if (grmask & (1 << gr)) {
                    iH[gr] = *(const bf16x8*)(ru + gr * 2048 + soff);
                    iL[gr] = *(const bf16x8*)(ru + gr * 2048 + 1024 + soff);
                }
        }
        // own-h terms: pure register operands; biases are the MFMA C-init
#pragma unroll
        for (int gr = 0; gr < 2; ++gr)
            if (grmask & (1 << gr)) {
#pragma unroll
                for (int t6 = 0; t6 < 4; ++t6) {
                    acc[gr][t6] = __builtin_amdgcn_mfma_f32_16x16x32_bf16(whh[t6], hfH[gr], bc[t6], 0, 0, 0);
                    acc[gr][t6] = __builtin_amdgcn_mfma_f32_16x16x32_bf16(whh[t6], hfL[gr], acc[gr][t6], 0, 0, 0);
                    acc[gr][t6] = __builtin_amdgcn_mfma_f32_16x16x32_bf16(whl[t6], hfH[gr], acc[gr][t6], 0, 0, 0);
                }
#pragma unroll
                for (int tt = 0; tt < 2; ++tt) {
                    accH[gr][tt] = __builtin_amdgcn_mfma_f32_16x16x32_bf16(whh[4 + tt], hfH[gr], bhn[tt], 0, 0, 0);
                    accH[gr][tt] = __builtin_amdgcn_mfma_f32_16x16x32_bf16(whh[4 + tt], hfL[gr], accH[gr][tt], 0, 0, 0);
                    accH[gr][tt] = __builtin_amdgcn_mfma_f32_16x16x32_bf16(whl[4 + tt], hfH[gr], accH[gr][tt], 0, 0, 0);
                }
            }
        // input part
        if (layer == 0) {
#pragma unroll
            for (int gr = 0; gr < 2; ++gr)
                if (grmask & (1 << gr)) {
                    float xv = xt[t][gr * 16 + b];
#pragma unroll
                    for (int t6 = 0; t6 < 4; ++t6) {
                        FragU u; u.s = wih[t6];
#pragma unroll
                        for (int r = 0; r < 4; ++r)
                            acc[gr][t6][r] = fmaf(u.f[r], xv, acc[gr][t6][r]);
                    }
#pragma unroll
                    for (int tt = 0; tt < 2; ++tt) {
                        FragU u; u.s = wih[4 + tt];
#pragma unroll
                        for (int r = 0; r < 4; ++r)
                            accX[gr][tt][r] = fmaf(u.f[r], xv, bxn[tt][r]);
                    }
                }
        } else {
#pragma unroll
            for (int gr = 0; gr < 2; ++gr)
                if (grmask & (1 << gr)) {
#pragma unroll
                    for (int t6 = 0; t6 < 4; ++t6) {
                        acc[gr][t6] = __builtin_amdgcn_mfma_f32_16x16x32_bf16(wih[t6], iH[gr], acc[gr][t6], 0, 0, 0);
                        acc[gr][t6] = __builtin_amdgcn_mfma_f32_16x16x32_bf16(wih[t6], iL[gr], acc[gr][t6], 0, 0, 0);
                        acc[gr][t6] = __builtin_amdgcn_mfma_f32_16x16x32_bf16(wil[t6], iH[gr], acc[gr][t6], 0, 0, 0);
                    }
#pragma unroll
                    for (int tt = 0; tt < 2; ++tt) {
                        accX[gr][tt] = __builtin_amdgcn_mfma_f32_16x16x32_bf16(wih[4 + tt], iH[gr], bxn[tt], 0, 0, 0);
                        accX[gr][tt] = __builtin_amdgcn_mfma_f32_16x16x32_bf16(wih[4 + tt], iL[gr], accX[gr][tt], 0, 0, 0);
                        accX[gr][tt] = __builtin_amdgcn_mfma_f32_16x16x32_bf16(wil[4 + tt], iH[gr], accX[gr][tt], 0, 0, 0);
                    }
                }
        }
        // gates (pre-scaled): Er=e^-rpre, Ez=e^-zpre, En=e^-2npre
        // r = 1/(1+Er); n = (1-En)/(1+En); h = [n*Ez + hp] / (1+Ez)
#pragma unroll
        for (int gr = 0; gr < 2; ++gr)
            if (grmask & (1 << gr)) {
                float hnew[8];
#pragma unroll
                for (int jj = 0; jj < 2; ++jj)
#pragma unroll
                    for (int r = 0; r < 4; ++r) {
                        float Er = exp2b(acc[gr][jj][r]);
                        float Ez = exp2b(acc[gr][2 + jj][r]);
                        float rg = rcpa(1.0f + Er);
                        float u  = fmaf(rg, accH[gr][jj][r], accX[gr][jj][r]);
                        float En = exp2b(u);
                        float en1 = 1.0f + En, ez1 = 1.0f + Ez;
                        float d   = rcpa(en1 * ez1);
                        float num = fmaf(hp[gr][jj * 4 + r], en1, (1.0f - En) * Ez);
                        hnew[jj * 4 + r] = num * d;
                    }
#pragma unroll
                for (int i2 = 0; i2 < 8; ++i2) hp[gr][i2] = hnew[i2];

                unsigned int h01, l01, h23, l23, h45, l45, h67, l67;
                pk_pair(hnew[0], hnew[1], h01, l01);
                pk_pair(hnew[2], hnew[3], h23, l23);
                pk_pair(hnew[4], hnew[5], h45, l45);
                pk_pair(hnew[6], hnew[7], h67, l67);
                FragU Hu, Lu;
                Hu.u[0] = h01; Hu.u[1] = h23; Hu.u[2] = h45; Hu.u[3] = h67;
                Lu.u[0] = l01; Lu.u[1] = l23; Lu.u[2] = l45; Lu.u[3] = l67;
                hfH[gr] = Hu.s; hfL[gr] = Lu.s;
                if (layer < L - 1) {
                    unsigned char* wp8 = sbase + ((layer * 4 + wp * 2 + st) << 12) + gr * 2048;
                    *(uint4*)(wp8 + soff)        = make_uint4(h01, h23, h45, h67);
                    *(uint4*)(wp8 + 1024 + soff) = make_uint4(l01, l23, l45, l67);
                }
            }
    };

    __syncthreads();

    for (int i = 0; i < NK; ++i) {
        int k = i - layer;            // local pair index
        if (0 <= k && k < NPAIR) {
            const int p = i & 1, q = p ^ 1;
            do_step(2 * k,     q, p, 0);
            do_step(2 * k + 1, q, p, 1);
        }
        __syncthreads();
    }

    // heads: per-(layer,group) partial over 32 hidden units, then cross-wave reduce
    {
        const int rb = g * 4;
#pragma unroll
        for (int hd = 0; hd < 3; ++hd) {
            const float* W = (hd == 0) ? Wk : (hd == 1) ? We : Wt;
#pragma unroll
            for (int gr = 0; gr < 2; ++gr)
                if (grmask & (1 << gr)) {
                    float s = 0.0f;
#pragma unroll
                    for (int jj = 0; jj < 2; ++jj)
#pragma unroll
                        for (int r = 0; r < 4; ++r)
                            s = fmaf(W[layer * H + jj * 16 + rb + r], hp[gr][jj * 4 + r], s);
                    s += __shfl_xor(s, 16, 64);
                    s += __shfl_xor(s, 32, 64);
                    if (g == 0) hpart[layer][hd][gr * 16 + b] = s;
                }
        }
        __syncthreads();
        if (wv < 3 && lane < BT) {
            int bb = lane;
            float s = (wv == 0) ? bk[0] : (wv == 1) ? be[0] : bt[0];
#pragma unroll
            for (int l = 0; l < L; ++l) s += hpart[l][wv][bb];
            out[wv * B + b0 + bb] = s;
        }
    }
}

extern "C" void kernel_launch(void* const* d_in, const int* in_sizes, int n_in,
                              void* d_out, int out_size, void* d_ws, size_t ws_size,
                              hipStream_t stream)
{
    const float* x    = (const float*)d_in[0];
    const float* Wih0 = (const float*)d_in[1];
    const float* Wih  = (const float*)d_in[2];
    const float* Whh  = (const float*)d_in[3];
    const float* bih  = (const float*)d_in[4];
    const float* bhh  = (const float*)d_in[5];
    const float* Wk   = (const float*)d_in[6];
    const float* bk   = (const float*)d_in[7];
    const float* We   = (const float*)d_in[8];
    const float* be   = (const float*)d_in[9];
    const float* Wt   = (const float*)d_in[10];
    const float* bt   = (const float*)d_in[11];
    float* out = (float*)d_out;

    const int B = in_sizes[0] / T_LEN;   // 16384

    unsigned short* WhFhi = (unsigned short*)d_ws;        // 6*6*64*8 bf16
    unsigned short* WhFlo = WhFhi + L * NT * 64 * 8;
    unsigned short* WiFhi = WhFlo + L * NT * 64 * 8;      // 5*6*64*8 bf16
    unsigned short* WiFlo = WiFhi + (L - 1) * NT * 64 * 8;

    const int nPack = (L * NT * 64) + ((L - 1) * NT * 64);  // 4224
    pack_frags<<<(nPack + 255) / 256, 256, 0, stream>>>(Whh, Wih, WhFhi, WhFlo, WiFhi, WiFlo);
    gru_mfma<<<B / BT, TPB, 0, stream>>>(x, Wih0, bih, bhh, WhFhi, WhFlo, WiFhi, WiFlo,
                                         Wk, bk, We, be, Wt, bt, out, B);
}